// Round 1
// baseline (180.032 us; speedup 1.0000x reference)
//
#include <hip/hip_runtime.h>
#include <hip/hip_bf16.h>
#include <stdint.h>

typedef __hip_bfloat16 bf16;
typedef __attribute__((ext_vector_type(8))) __bf16 frag8;
typedef __attribute__((ext_vector_type(4))) float f32x4;

#define GLDS16(gsrc, ldst)                                                        \
  __builtin_amdgcn_global_load_lds(                                               \
      (const __attribute__((address_space(1))) void*)(gsrc),                      \
      (__attribute__((address_space(3))) void*)(ldst), 16, 0, 0)

// ---------------- helpers ----------------
__device__ inline float wred_sum(float v) {
#pragma unroll
  for (int o = 32; o; o >>= 1) v += __shfl_down(v, o);
  return v;
}
__device__ inline float wred_max(float v) {
#pragma unroll
  for (int o = 32; o; o >>= 1) v = fmaxf(v, __shfl_down(v, o));
  return v;
}

// ---------------- 0. bulk fp32 -> bf16 convert (weights + roi) ----------------
__global__ __launch_bounds__(256) void convert_all(
    const float* __restrict__ s0, bf16* __restrict__ d0, int n0,
    const float* __restrict__ s1, bf16* __restrict__ d1, int n1,
    const float* __restrict__ s2, bf16* __restrict__ d2, int n2,
    const float* __restrict__ s3, bf16* __restrict__ d3, int n3,
    const float* __restrict__ s4, bf16* __restrict__ d4, int n4) {
  int i = blockIdx.x * 256 + threadIdx.x;
  if (i < n0) { d0[i] = __float2bfloat16(s0[i]); return; } i -= n0;
  if (i < n1) { d1[i] = __float2bfloat16(s1[i]); return; } i -= n1;
  if (i < n2) { d2[i] = __float2bfloat16(s2[i]); return; } i -= n2;
  if (i < n3) { d3[i] = __float2bfloat16(s3[i]); return; } i -= n3;
  if (i < n4) { d4[i] = __float2bfloat16(s4[i]); }
}

// ---------------- 1. X [32][768][1204] fp32 -> Xt [32][1280][768] bf16 --------
__global__ __launch_bounds__(256) void transpose_x(const float* __restrict__ X,
                                                   bf16* __restrict__ Xt) {
  __shared__ float t[32][33];
  int b = blockIdx.z;
  int p0 = blockIdx.x * 32, c0 = blockIdx.y * 32;
  int tx = threadIdx.x & 31, ty = threadIdx.x >> 5;
#pragma unroll
  for (int i = 0; i < 4; ++i) {
    int c = c0 + ty + i * 8;
    int pp = p0 + tx;
    t[ty + i * 8][tx] = (pp < 1204) ? X[((long)b * 768 + c) * 1204 + pp] : 0.f;
  }
  __syncthreads();
#pragma unroll
  for (int i = 0; i < 4; ++i) {
    int pl = ty + i * 8;
    Xt[((long)b * 1280 + p0 + pl) * 768 + c0 + tx] = __float2bfloat16(t[tx][pl]);
  }
}

// ---------------- 2. generic TN MFMA GEMM: C[m][n] = sum_k A[m][k]B[n][k] ------
// 128x128 tile, BK=32, 4 waves (2x2 of 64x64), m97-style global_load_lds staging.
template <bool BIAS_ROW, bool RELU, bool OUT_BF16>
__global__ __launch_bounds__(256) void gemm_tn(
    const bf16* __restrict__ A, long sA, const bf16* __restrict__ B, long sB,
    void* __restrict__ C, long sC, int K, int ldc, const float* __restrict__ bias) {
  int bz = blockIdx.z;
  int n0 = blockIdx.x * 128, m0 = blockIdx.y * 128;
  const bf16* Ab = A + bz * sA + (long)m0 * K;
  const bf16* Bb = B + bz * sB + (long)n0 * K;
  __shared__ __align__(16) bf16 lA[128 * 32];
  __shared__ __align__(16) bf16 lB[128 * 32];
  int tid = threadIdx.x;
  int w = tid >> 6, lane = tid & 63;
  int wm = w >> 1, wn = w & 1;
  int lr = lane & 15, kg = lane >> 4;
  f32x4 acc[4][4] = {};
  for (int k0 = 0; k0 < K; k0 += 32) {
#pragma unroll
    for (int i = 0; i < 2; ++i) {
      int off = w * 2048 + i * 1024 + lane * 16;   // byte offset within 8 KB tile
      int row = off >> 6, kb = off & 63;           // 64 B per LDS row
      long gbyte = (long)row * (K * 2) + (long)k0 * 2 + kb;
      GLDS16((const char*)Ab + gbyte, (char*)lA + w * 2048 + i * 1024);
      GLDS16((const char*)Bb + gbyte, (char*)lB + w * 2048 + i * 1024);
    }
    __syncthreads();
    frag8 af[4], bv[4];
#pragma unroll
    for (int mi = 0; mi < 4; ++mi)
      af[mi] = *(const frag8*)((const char*)lA + (wm * 64 + mi * 16 + lr) * 64 + kg * 16);
#pragma unroll
    for (int ni = 0; ni < 4; ++ni)
      bv[ni] = *(const frag8*)((const char*)lB + (wn * 64 + ni * 16 + lr) * 64 + kg * 16);
#pragma unroll
    for (int mi = 0; mi < 4; ++mi)
#pragma unroll
      for (int ni = 0; ni < 4; ++ni)
        acc[mi][ni] = __builtin_amdgcn_mfma_f32_16x16x32_bf16(af[mi], bv[ni], acc[mi][ni], 0, 0, 0);
    __syncthreads();
  }
#pragma unroll
  for (int mi = 0; mi < 4; ++mi)
#pragma unroll
    for (int ni = 0; ni < 4; ++ni)
#pragma unroll
      for (int j = 0; j < 4; ++j) {
        int row = m0 + wm * 64 + mi * 16 + kg * 4 + j;   // C row = (lane>>4)*4 + reg
        int col = n0 + wn * 64 + ni * 16 + lr;           // C col = lane&15
        float v = acc[mi][ni][j];
        v += BIAS_ROW ? bias[row] : bias[col];
        if (RELU) v = fmaxf(v, 0.f);
        long idx = (long)bz * sC + (long)row * ldc + col;
        if constexpr (OUT_BF16) ((bf16*)C)[idx] = __float2bfloat16(v);
        else ((float*)C)[idx] = v;
      }
}

// ---------------- 3. logits[b][n][p] = sum_c emb[b][n][c] * img[b][c][p] -------
__global__ __launch_bounds__(256) void logits_k(const bf16* __restrict__ img,
                                                const float* __restrict__ emb,
                                                float* __restrict__ lgt) {
  int b = blockIdx.x;
  __shared__ float e[3072];
  const float* eb = emb + (long)b * 3072;
  for (int i = threadIdx.x; i < 3072; i += 256) e[i] = eb[i];
  __syncthreads();
  int p = blockIdx.y * 256 + threadIdx.x;
  if (p >= 1204) return;
  const bf16* ib = img + (long)b * 256 * 1280 + p;
  float acc[12] = {};
#pragma unroll 4
  for (int c = 0; c < 256; ++c) {
    float xv = __bfloat162float(ib[(long)c * 1280]);
#pragma unroll
    for (int n = 0; n < 12; ++n) acc[n] += e[n * 256 + c] * xv;
  }
#pragma unroll
  for (int n = 0; n < 12; ++n) lgt[((long)b * 12 + n) * 1204 + p] = acc[n];
}

// ---------------- 4. row softmax -> A_sm [32][16][1280] bf16 (zero padded) -----
__global__ __launch_bounds__(256) void softmax_k(const float* __restrict__ lgt,
                                                 bf16* __restrict__ am) {
  int b = blockIdx.x, n = blockIdx.y, tid = threadIdx.x;
  bf16* row = am + ((long)b * 16 + n) * 1280;
  if (n >= 12) {  // pad rows 12..15 = 0
    for (int i = tid; i < 1280; i += 256) row[i] = __float2bfloat16(0.f);
    return;
  }
  const float* lr = lgt + ((long)b * 12 + n) * 1204;
  float vals[5];
  float m = -3.0e38f;
#pragma unroll
  for (int i = 0; i < 5; ++i) {
    int pp = tid + i * 256;
    vals[i] = (pp < 1204) ? lr[pp] : -3.0e38f;
    m = fmaxf(m, vals[i]);
  }
  m = wred_max(m);
  __shared__ float rd[4];
  int w = tid >> 6, lane = tid & 63;
  if (lane == 0) rd[w] = m;
  __syncthreads();
  m = fmaxf(fmaxf(rd[0], rd[1]), fmaxf(rd[2], rd[3]));
  float s = 0.f;
#pragma unroll
  for (int i = 0; i < 5; ++i) {
    int pp = tid + i * 256;
    vals[i] = (pp < 1204) ? __expf(vals[i] - m) : 0.f;
    s += vals[i];
  }
  s = wred_sum(s);
  __syncthreads();
  if (lane == 0) rd[w] = s;
  __syncthreads();
  s = rd[0] + rd[1] + rd[2] + rd[3];
  float inv = 1.f / s;
#pragma unroll
  for (int i = 0; i < 5; ++i) {
    int pp = tid + i * 256;
    row[pp] = __float2bfloat16((pp < 1204) ? vals[i] * inv : 0.f);
  }
}

// ---------------- 5. ctxT[c][n] per b: MFMA M=256,N=16,K=1280 ------------------
__global__ __launch_bounds__(256) void ctx_k(const bf16* __restrict__ img,
                                             const bf16* __restrict__ am,
                                             float* __restrict__ ctx) {
  int b = blockIdx.x;
  const bf16* Ab = img + (long)b * 256 * 1280;
  const bf16* Bb = am + (long)b * 16 * 1280;
  __shared__ __align__(16) bf16 lA[256 * 32];
  __shared__ __align__(16) bf16 lB[16 * 32];
  int tid = threadIdx.x, w = tid >> 6, lane = tid & 63;
  int lr = lane & 15, kg = lane >> 4;
  f32x4 acc[4] = {};
  for (int k0 = 0; k0 < 1280; k0 += 32) {
#pragma unroll
    for (int i = 0; i < 4; ++i) {
      int off = w * 4096 + i * 1024 + lane * 16;
      int row = off >> 6, kb = off & 63;
      GLDS16((const char*)Ab + (long)row * 2560 + k0 * 2 + kb,
             (char*)lA + w * 4096 + i * 1024);
    }
    if (w == 0) {
      int off = lane * 16, row = off >> 6, kb = off & 63;
      GLDS16((const char*)Bb + (long)row * 2560 + k0 * 2 + kb, (char*)lB);
    }
    __syncthreads();
    frag8 bv = *(const frag8*)((const char*)lB + lr * 64 + kg * 16);
#pragma unroll
    for (int mi = 0; mi < 4; ++mi) {
      frag8 av = *(const frag8*)((const char*)lA + (w * 64 + mi * 16 + lr) * 64 + kg * 16);
      acc[mi] = __builtin_amdgcn_mfma_f32_16x16x32_bf16(av, bv, acc[mi], 0, 0, 0);
    }
    __syncthreads();
  }
  int n = lr;
  if (n < 12) {
#pragma unroll
    for (int mi = 0; mi < 4; ++mi)
#pragma unroll
      for (int j = 0; j < 4; ++j)
        ctx[((long)b * 12 + n) * 256 + (w * 64 + mi * 16 + kg * 4 + j)] = acc[mi][j];
  }
}

// ---------------- 6. LayerNorm over 256 (one row per block) --------------------
__global__ __launch_bounds__(256) void ln_k(const float* __restrict__ a,
                                            const float* __restrict__ bb,
                                            const float* __restrict__ g,
                                            const float* __restrict__ be,
                                            float* __restrict__ of,
                                            bf16* __restrict__ ob) {
  int r = blockIdx.x, c = threadIdx.x;
  long idx = (long)r * 256 + c;
  float v = a[idx] + bb[idx];
  float s = wred_sum(v);
  float s2 = wred_sum(v * v);
  __shared__ float r1[4], r2[4];
  int w = c >> 6, lane = c & 63;
  if (lane == 0) { r1[w] = s; r2[w] = s2; }
  __syncthreads();
  float st = r1[0] + r1[1] + r1[2] + r1[3];
  float s2t = r2[0] + r2[1] + r2[2] + r2[3];
  float mean = st * (1.f / 256.f);
  float var = s2t * (1.f / 256.f) - mean * mean;
  float rs = rsqrtf(var + 1e-5f);
  float y = (v - mean) * rs * g[c] + be[c];
  if (of) of[idx] = y;
  if (ob) ob[idx] = __float2bfloat16(y);
}

// ---------------- launcher -----------------------------------------------------
extern "C" void kernel_launch(void* const* d_in, const int* in_sizes, int n_in,
                              void* d_out, int out_size, void* d_ws, size_t ws_size,
                              hipStream_t stream) {
  const float* roi   = (const float*)d_in[0];
  const float* imgf  = (const float*)d_in[1];
  const float* convw = (const float*)d_in[2];
  const float* convb = (const float*)d_in[3];
  const float* embw  = (const float*)d_in[4];
  const float* embb  = (const float*)d_in[5];
  const float* ln1g  = (const float*)d_in[6];
  const float* ln1b  = (const float*)d_in[7];
  const float* w1    = (const float*)d_in[8];
  const float* b1    = (const float*)d_in[9];
  const float* w2    = (const float*)d_in[10];
  const float* b2    = (const float*)d_in[11];
  const float* ln2g  = (const float*)d_in[12];
  const float* ln2b  = (const float*)d_in[13];
  float* out = (float*)d_out;

  char* p = (char*)d_ws;
  size_t off = 0;
  auto take = [&](size_t sz) -> char* {
    char* r = p + off;
    off += (sz + 255) & ~(size_t)255;
    return r;
  };
  bf16*  Xt   = (bf16*)take((size_t)32 * 1280 * 768 * 2);   // 62.9 MB
  bf16*  img  = (bf16*)take((size_t)32 * 256 * 1280 * 2);   // 21.0 MB
  bf16*  cwb  = (bf16*)take((size_t)256 * 768 * 2);
  bf16*  ewb  = (bf16*)take((size_t)256 * 1024 * 2);
  bf16*  w1b  = (bf16*)take((size_t)256 * 256 * 2);
  bf16*  w2b  = (bf16*)take((size_t)256 * 256 * 2);
  bf16*  roib = (bf16*)take((size_t)384 * 1024 * 2);
  float* emb  = (float*)take((size_t)384 * 256 * 4);
  float* lgt  = (float*)take((size_t)384 * 1204 * 4);
  bf16*  am   = (bf16*)take((size_t)32 * 16 * 1280 * 2);
  float* ctx  = (float*)take((size_t)384 * 256 * 4);
  float* x    = (float*)take((size_t)384 * 256 * 4);
  bf16*  xb   = (bf16*)take((size_t)384 * 256 * 2);
  bf16*  h1   = (bf16*)take((size_t)384 * 256 * 2);
  float* h    = (float*)take((size_t)384 * 256 * 4);

  // 0. converts (weights + roi): 983040 elements
  {
    int total = 196608 + 262144 + 65536 + 65536 + 393216;
    convert_all<<<(total + 255) / 256, 256, 0, stream>>>(
        convw, cwb, 196608, embw, ewb, 262144, w1, w1b, 65536, w2, w2b, 65536,
        roi, roib, 393216);
  }
  // 1. transpose + convert image_feature
  transpose_x<<<dim3(40, 24, 32), 256, 0, stream>>>(imgf, Xt);
  // 2. conv GEMM: img[b][o][p] = sum_c W[o][c]*Xt[b][p][c] + conv_b[o]
  gemm_tn<true, false, true><<<dim3(10, 2, 32), 256, 0, stream>>>(
      cwb, 0, Xt, (long)1280 * 768, img, (long)256 * 1280, 768, 1280, convb);
  // 3. emb GEMM: emb[384][256] fp32
  gemm_tn<false, false, false><<<dim3(2, 3, 1), 256, 0, stream>>>(
      roib, 0, ewb, 0, emb, 0, 1024, 256, embb);
  // 4. logits
  logits_k<<<dim3(32, 5), 256, 0, stream>>>(img, emb, lgt);
  // 5. softmax -> A_sm (bf16, padded with zeros)
  softmax_k<<<dim3(32, 16), 256, 0, stream>>>(lgt, am);
  // 6. ctx
  ctx_k<<<32, 256, 0, stream>>>(img, am, ctx);
  // 7. LN1 -> x (fp32) + xb (bf16)
  ln_k<<<384, 256, 0, stream>>>(ctx, emb, ln1g, ln1b, x, xb);
  // 8/9. FFN
  gemm_tn<false, true, true><<<dim3(2, 3, 1), 256, 0, stream>>>(
      xb, 0, w1b, 0, h1, 0, 256, 256, b1);
  gemm_tn<false, false, false><<<dim3(2, 3, 1), 256, 0, stream>>>(
      h1, 0, w2b, 0, h, 0, 256, 256, b2);
  // 10. LN2 -> out
  ln_k<<<384, 256, 0, stream>>>(x, h, ln2g, ln2b, out, nullptr);
}

// Round 2
// 137.798 us; speedup vs baseline: 1.3065x; 1.3065x over previous
//
#include <hip/hip_runtime.h>
#include <hip/hip_bf16.h>
#include <stdint.h>

typedef __hip_bfloat16 bf16;
typedef __attribute__((ext_vector_type(8))) __bf16 frag8;
typedef __attribute__((ext_vector_type(4))) float f32x4;

#define GLDS16(gsrc, ldst)                                                        \
  __builtin_amdgcn_global_load_lds(                                               \
      (const __attribute__((address_space(1))) void*)(gsrc),                      \
      (__attribute__((address_space(3))) void*)(ldst), 16, 0, 0)

// ---------------- helpers ----------------
__device__ inline float wred_sum(float v) {
#pragma unroll
  for (int o = 32; o; o >>= 1) v += __shfl_down(v, o);
  return v;
}
__device__ inline float wred_max(float v) {
#pragma unroll
  for (int o = 32; o; o >>= 1) v = fmaxf(v, __shfl_down(v, o));
  return v;
}
__device__ inline unsigned short bits_of(bf16 h) { return *(unsigned short*)&h; }

// ---------------- 0. bulk fp32 -> bf16 convert (weights + roi) ----------------
__global__ __launch_bounds__(256) void convert_all(
    const float* __restrict__ s0, bf16* __restrict__ d0, int n0,
    const float* __restrict__ s1, bf16* __restrict__ d1, int n1,
    const float* __restrict__ s2, bf16* __restrict__ d2, int n2,
    const float* __restrict__ s3, bf16* __restrict__ d3, int n3,
    const float* __restrict__ s4, bf16* __restrict__ d4, int n4) {
  int i = blockIdx.x * 256 + threadIdx.x;
  if (i < n0) { d0[i] = __float2bfloat16(s0[i]); return; } i -= n0;
  if (i < n1) { d1[i] = __float2bfloat16(s1[i]); return; } i -= n1;
  if (i < n2) { d2[i] = __float2bfloat16(s2[i]); return; } i -= n2;
  if (i < n3) { d3[i] = __float2bfloat16(s3[i]); return; } i -= n3;
  if (i < n4) { d4[i] = __float2bfloat16(s4[i]); }
}

// ---------------- 1. FUSED conv: img[b][o][p] = sum_c W[o][c] X[b][c][p] + bias[o]
// BM=256 (all o), BN=128 p, BK=32. 512 threads = 8 waves (4m x 2n), wave tile 64x64.
// X is fp32 [b][c][p]; staged via registers with convert + transposed, XOR-swizzled
// LDS write (lB[p][c], byte ^= ((p>>3)&7)<<4). W is pre-converted bf16, GLDS16 linear.
__global__ __launch_bounds__(512) void conv_fused(
    const float* __restrict__ X, const bf16* __restrict__ W,
    const float* __restrict__ bias, bf16* __restrict__ img) {
  int b = blockIdx.y;
  int p0 = blockIdx.x * 128;
  __shared__ __align__(16) bf16 lA[256 * 32];   // 16 KB, [o][c], 64 B rows
  __shared__ __align__(16) bf16 lB[128 * 32];   // 8 KB,  [p][c] swizzled
  int tid = threadIdx.x, w = tid >> 6, lane = tid & 63;
  int wm = w >> 1, wn = w & 1;
  int lr = lane & 15, kg = lane >> 4;
  int sc = (tid >> 5) * 2;        // staging c (2 rows)
  int spq = (tid & 31) * 4;       // staging p quad
  const int prem = 1204 - p0;
  f32x4 acc[4][4] = {};
  for (int k0 = 0; k0 < 768; k0 += 32) {
    // A staging: 16 KB via GLDS16, linear
#pragma unroll
    for (int i = 0; i < 2; ++i) {
      int off = w * 1024 + i * 8192 + lane * 16;
      int row = off >> 6, kb = off & 63;
      GLDS16((const char*)W + (long)row * 1536 + k0 * 2 + kb,
             (char*)lA + w * 1024 + i * 8192);
    }
    // B staging: X fp32 -> bf16, transposed into lB[p][c] with XOR swizzle
    const float* xr = X + ((long)b * 768 + k0 + sc) * 1204 + p0 + spq;
    float v0[4], v1[4];
    if (prem >= 128) {
      float4 a0 = *(const float4*)xr;
      float4 a1 = *(const float4*)(xr + 1204);
      v0[0] = a0.x; v0[1] = a0.y; v0[2] = a0.z; v0[3] = a0.w;
      v1[0] = a1.x; v1[1] = a1.y; v1[2] = a1.z; v1[3] = a1.w;
    } else {
#pragma unroll
      for (int j = 0; j < 4; ++j) {
        bool ok = (spq + j) < prem;
        v0[j] = ok ? xr[j] : 0.f;
        v1[j] = ok ? xr[1204 + j] : 0.f;
      }
    }
#pragma unroll
    for (int j = 0; j < 4; ++j) {
      int p = spq + j;
      unsigned pk = (unsigned)bits_of(__float2bfloat16(v0[j]))
                  | ((unsigned)bits_of(__float2bfloat16(v1[j])) << 16);
      int byte = (p << 6) + sc * 2;
      byte ^= ((p >> 3) & 7) << 4;
      *(unsigned*)((char*)lB + byte) = pk;
    }
    __syncthreads();
    frag8 af[4], bv[4];
#pragma unroll
    for (int mi = 0; mi < 4; ++mi)
      af[mi] = *(const frag8*)((const char*)lA + (wm * 64 + mi * 16 + lr) * 64 + kg * 16);
#pragma unroll
    for (int ni = 0; ni < 4; ++ni) {
      int pl = wn * 64 + ni * 16 + lr;
      int byte = (pl << 6) + kg * 16;
      byte ^= ((pl >> 3) & 7) << 4;
      bv[ni] = *(const frag8*)((const char*)lB + byte);
    }
#pragma unroll
    for (int mi = 0; mi < 4; ++mi)
#pragma unroll
      for (int ni = 0; ni < 4; ++ni)
        acc[mi][ni] = __builtin_amdgcn_mfma_f32_16x16x32_bf16(af[mi], bv[ni], acc[mi][ni], 0, 0, 0);
    __syncthreads();
  }
#pragma unroll
  for (int mi = 0; mi < 4; ++mi)
#pragma unroll
    for (int ni = 0; ni < 4; ++ni)
#pragma unroll
      for (int j = 0; j < 4; ++j) {
        int o = wm * 64 + mi * 16 + kg * 4 + j;
        int p = p0 + wn * 64 + ni * 16 + lr;
        float v = acc[mi][ni][j] + bias[o];
        img[((long)b * 256 + o) * 1280 + p] = __float2bfloat16(v);
      }
}

// ---------------- 2. generic TN MFMA GEMM: C[m][n] = sum_k A[m][k]B[n][k] ------
template <bool BIAS_ROW, bool RELU, bool OUT_BF16>
__global__ __launch_bounds__(256) void gemm_tn(
    const bf16* __restrict__ A, long sA, const bf16* __restrict__ B, long sB,
    void* __restrict__ C, long sC, int K, int ldc, const float* __restrict__ bias) {
  int bz = blockIdx.z;
  int n0 = blockIdx.x * 128, m0 = blockIdx.y * 128;
  const bf16* Ab = A + bz * sA + (long)m0 * K;
  const bf16* Bb = B + bz * sB + (long)n0 * K;
  __shared__ __align__(16) bf16 lA[128 * 32];
  __shared__ __align__(16) bf16 lB[128 * 32];
  int tid = threadIdx.x;
  int w = tid >> 6, lane = tid & 63;
  int wm = w >> 1, wn = w & 1;
  int lr = lane & 15, kg = lane >> 4;
  f32x4 acc[4][4] = {};
  for (int k0 = 0; k0 < K; k0 += 32) {
#pragma unroll
    for (int i = 0; i < 2; ++i) {
      int off = w * 2048 + i * 1024 + lane * 16;
      int row = off >> 6, kb = off & 63;
      long gbyte = (long)row * (K * 2) + (long)k0 * 2 + kb;
      GLDS16((const char*)Ab + gbyte, (char*)lA + w * 2048 + i * 1024);
      GLDS16((const char*)Bb + gbyte, (char*)lB + w * 2048 + i * 1024);
    }
    __syncthreads();
    frag8 af[4], bv[4];
#pragma unroll
    for (int mi = 0; mi < 4; ++mi)
      af[mi] = *(const frag8*)((const char*)lA + (wm * 64 + mi * 16 + lr) * 64 + kg * 16);
#pragma unroll
    for (int ni = 0; ni < 4; ++ni)
      bv[ni] = *(const frag8*)((const char*)lB + (wn * 64 + ni * 16 + lr) * 64 + kg * 16);
#pragma unroll
    for (int mi = 0; mi < 4; ++mi)
#pragma unroll
      for (int ni = 0; ni < 4; ++ni)
        acc[mi][ni] = __builtin_amdgcn_mfma_f32_16x16x32_bf16(af[mi], bv[ni], acc[mi][ni], 0, 0, 0);
    __syncthreads();
  }
#pragma unroll
  for (int mi = 0; mi < 4; ++mi)
#pragma unroll
    for (int ni = 0; ni < 4; ++ni)
#pragma unroll
      for (int j = 0; j < 4; ++j) {
        int row = m0 + wm * 64 + mi * 16 + kg * 4 + j;
        int col = n0 + wn * 64 + ni * 16 + lr;
        float v = acc[mi][ni][j];
        v += BIAS_ROW ? bias[row] : bias[col];
        if (RELU) v = fmaxf(v, 0.f);
        long idx = (long)bz * sC + (long)row * ldc + col;
        if constexpr (OUT_BF16) ((bf16*)C)[idx] = __float2bfloat16(v);
        else ((float*)C)[idx] = v;
      }
}

// ---------------- 3. logits[b][n][p] = sum_c emb[b][n][c] * img[b][c][p] -------
__global__ __launch_bounds__(256) void logits_k(const bf16* __restrict__ img,
                                                const float* __restrict__ emb,
                                                float* __restrict__ lgt) {
  int b = blockIdx.x;
  __shared__ float e[3072];
  const float* eb = emb + (long)b * 3072;
  for (int i = threadIdx.x; i < 3072; i += 256) e[i] = eb[i];
  __syncthreads();
  int p = blockIdx.y * 256 + threadIdx.x;
  if (p >= 1204) return;
  const bf16* ib = img + (long)b * 256 * 1280 + p;
  float acc[12] = {};
#pragma unroll 4
  for (int c = 0; c < 256; ++c) {
    float xv = __bfloat162float(ib[(long)c * 1280]);
#pragma unroll
    for (int n = 0; n < 12; ++n) acc[n] += e[n * 256 + c] * xv;
  }
#pragma unroll
  for (int n = 0; n < 12; ++n) lgt[((long)b * 12 + n) * 1204 + p] = acc[n];
}

// ---------------- 4. row softmax -> A_sm [32][16][1280] bf16 (zero padded) -----
__global__ __launch_bounds__(256) void softmax_k(const float* __restrict__ lgt,
                                                 bf16* __restrict__ am) {
  int b = blockIdx.x, n = blockIdx.y, tid = threadIdx.x;
  bf16* row = am + ((long)b * 16 + n) * 1280;
  if (n >= 12) {
    for (int i = tid; i < 1280; i += 256) row[i] = __float2bfloat16(0.f);
    return;
  }
  const float* lr = lgt + ((long)b * 12 + n) * 1204;
  float vals[5];
  float m = -3.0e38f;
#pragma unroll
  for (int i = 0; i < 5; ++i) {
    int pp = tid + i * 256;
    vals[i] = (pp < 1204) ? lr[pp] : -3.0e38f;
    m = fmaxf(m, vals[i]);
  }
  m = wred_max(m);
  __shared__ float rd[4];
  int w = tid >> 6, lane = tid & 63;
  if (lane == 0) rd[w] = m;
  __syncthreads();
  m = fmaxf(fmaxf(rd[0], rd[1]), fmaxf(rd[2], rd[3]));
  float s = 0.f;
#pragma unroll
  for (int i = 0; i < 5; ++i) {
    int pp = tid + i * 256;
    vals[i] = (pp < 1204) ? __expf(vals[i] - m) : 0.f;
    s += vals[i];
  }
  s = wred_sum(s);
  __syncthreads();
  if (lane == 0) rd[w] = s;
  __syncthreads();
  s = rd[0] + rd[1] + rd[2] + rd[3];
  float inv = 1.f / s;
#pragma unroll
  for (int i = 0; i < 5; ++i) {
    int pp = tid + i * 256;
    row[pp] = __float2bfloat16((pp < 1204) ? vals[i] * inv : 0.f);
  }
}

// ---------------- 5. ctx split-K: cpart[kc][b*12+n][c], K chunk = 256 ----------
__global__ __launch_bounds__(256) void ctx_split(const bf16* __restrict__ img,
                                                 const bf16* __restrict__ am,
                                                 float* __restrict__ cpart) {
  int b = blockIdx.x, kc = blockIdx.y;
  const bf16* Ab = img + (long)b * 256 * 1280;
  const bf16* Bb = am + (long)b * 16 * 1280;
  __shared__ __align__(16) bf16 lA[256 * 32];
  __shared__ __align__(16) bf16 lB[16 * 32];
  int tid = threadIdx.x, w = tid >> 6, lane = tid & 63;
  int lr = lane & 15, kg = lane >> 4;
  f32x4 acc[4] = {};
  int kend = kc * 256 + 256;
  for (int k0 = kc * 256; k0 < kend; k0 += 32) {
#pragma unroll
    for (int i = 0; i < 4; ++i) {
      int off = w * 4096 + i * 1024 + lane * 16;
      int row = off >> 6, kb = off & 63;
      GLDS16((const char*)Ab + (long)row * 2560 + k0 * 2 + kb,
             (char*)lA + w * 4096 + i * 1024);
    }
    if (w == 0) {
      int off = lane * 16, row = off >> 6, kb = off & 63;
      GLDS16((const char*)Bb + (long)row * 2560 + k0 * 2 + kb, (char*)lB);
    }
    __syncthreads();
    frag8 bv = *(const frag8*)((const char*)lB + lr * 64 + kg * 16);
#pragma unroll
    for (int mi = 0; mi < 4; ++mi) {
      frag8 av = *(const frag8*)((const char*)lA + (w * 64 + mi * 16 + lr) * 64 + kg * 16);
      acc[mi] = __builtin_amdgcn_mfma_f32_16x16x32_bf16(av, bv, acc[mi], 0, 0, 0);
    }
    __syncthreads();
  }
  int n = lr;
  if (n < 12) {
#pragma unroll
    for (int mi = 0; mi < 4; ++mi)
#pragma unroll
      for (int j = 0; j < 4; ++j)
        cpart[((long)kc * 384 + b * 12 + n) * 256 + (w * 64 + mi * 16 + kg * 4 + j)] =
            acc[mi][j];
  }
}

// ---------------- 6. LayerNorm over 256; a = sum of nparts slices + bb ---------
__global__ __launch_bounds__(256) void ln_k(const float* __restrict__ a, int nparts,
                                            long pstride, const float* __restrict__ bb,
                                            const float* __restrict__ g,
                                            const float* __restrict__ be,
                                            float* __restrict__ of,
                                            bf16* __restrict__ ob) {
  int r = blockIdx.x, c = threadIdx.x;
  long idx = (long)r * 256 + c;
  float v = bb[idx];
  for (int q = 0; q < nparts; ++q) v += a[idx + q * pstride];
  float s = wred_sum(v);
  float s2 = wred_sum(v * v);
  __shared__ float r1[4], r2[4];
  int w = c >> 6, lane = c & 63;
  if (lane == 0) { r1[w] = s; r2[w] = s2; }
  __syncthreads();
  float st = r1[0] + r1[1] + r1[2] + r1[3];
  float s2t = r2[0] + r2[1] + r2[2] + r2[3];
  float mean = st * (1.f / 256.f);
  float var = s2t * (1.f / 256.f) - mean * mean;
  float rs = rsqrtf(var + 1e-5f);
  float y = (v - mean) * rs * g[c] + be[c];
  if (of) of[idx] = y;
  if (ob) ob[idx] = __float2bfloat16(y);
}

// ---------------- launcher -----------------------------------------------------
extern "C" void kernel_launch(void* const* d_in, const int* in_sizes, int n_in,
                              void* d_out, int out_size, void* d_ws, size_t ws_size,
                              hipStream_t stream) {
  const float* roi   = (const float*)d_in[0];
  const float* imgf  = (const float*)d_in[1];
  const float* convw = (const float*)d_in[2];
  const float* convb = (const float*)d_in[3];
  const float* embw  = (const float*)d_in[4];
  const float* embb  = (const float*)d_in[5];
  const float* ln1g  = (const float*)d_in[6];
  const float* ln1b  = (const float*)d_in[7];
  const float* w1    = (const float*)d_in[8];
  const float* b1    = (const float*)d_in[9];
  const float* w2    = (const float*)d_in[10];
  const float* b2    = (const float*)d_in[11];
  const float* ln2g  = (const float*)d_in[12];
  const float* ln2b  = (const float*)d_in[13];
  float* out = (float*)d_out;

  char* p = (char*)d_ws;
  size_t off = 0;
  auto take = [&](size_t sz) -> char* {
    char* r = p + off;
    off += (sz + 255) & ~(size_t)255;
    return r;
  };
  bf16*  img   = (bf16*)take((size_t)32 * 256 * 1280 * 2);   // 21.0 MB
  bf16*  cwb   = (bf16*)take((size_t)256 * 768 * 2);
  bf16*  ewb   = (bf16*)take((size_t)256 * 1024 * 2);
  bf16*  w1b   = (bf16*)take((size_t)256 * 256 * 2);
  bf16*  w2b   = (bf16*)take((size_t)256 * 256 * 2);
  bf16*  roib  = (bf16*)take((size_t)384 * 1024 * 2);
  float* emb   = (float*)take((size_t)384 * 256 * 4);
  float* lgt   = (float*)take((size_t)384 * 1204 * 4);
  bf16*  am    = (bf16*)take((size_t)32 * 16 * 1280 * 2);
  float* cpart = (float*)take((size_t)5 * 384 * 256 * 4);
  float* x     = (float*)take((size_t)384 * 256 * 4);
  bf16*  xb    = (bf16*)take((size_t)384 * 256 * 2);
  bf16*  h1    = (bf16*)take((size_t)384 * 256 * 2);
  float* h     = (float*)take((size_t)384 * 256 * 4);

  // 0. converts (weights + roi)
  {
    int total = 196608 + 262144 + 65536 + 65536 + 393216;
    convert_all<<<(total + 255) / 256, 256, 0, stream>>>(
        convw, cwb, 196608, embw, ewb, 262144, w1, w1b, 65536, w2, w2b, 65536,
        roi, roib, 393216);
  }
  // 1. fused transpose+convert+conv GEMM
  conv_fused<<<dim3(10, 32), 512, 0, stream>>>(imgf, cwb, convb, img);
  // 2. emb GEMM: emb[384][256] fp32
  gemm_tn<false, false, false><<<dim3(2, 3, 1), 256, 0, stream>>>(
      roib, 0, ewb, 0, emb, 0, 1024, 256, embb);
  // 3. logits
  logits_k<<<dim3(32, 5), 256, 0, stream>>>(img, emb, lgt);
  // 4. softmax -> A_sm (bf16, padded with zeros)
  softmax_k<<<dim3(32, 16), 256, 0, stream>>>(lgt, am);
  // 5. ctx split-K over 5 chunks of 256
  ctx_split<<<dim3(32, 5), 256, 0, stream>>>(img, am, cpart);
  // 6. LN1: x = LN(sum(cpart) + emb)
  ln_k<<<384, 256, 0, stream>>>(cpart, 5, (long)384 * 256, emb, ln1g, ln1b, x, xb);
  // 7/8. FFN
  gemm_tn<false, true, true><<<dim3(2, 3, 1), 256, 0, stream>>>(
      xb, 0, w1b, 0, h1, 0, 256, 256, b1);
  gemm_tn<false, false, false><<<dim3(2, 3, 1), 256, 0, stream>>>(
      h1, 0, w2b, 0, h, 0, 256, 256, b2);
  // 9. LN2 -> out
  ln_k<<<384, 256, 0, stream>>>(h, 1, 0, x, ln2g, ln2b, out, nullptr);
}